// Round 6
// baseline (814.109 us; speedup 1.0000x reference)
//
#include <hip/hip_runtime.h>
#include <math.h>

#define NB   256
#define NPG  2048
#define DD   128
#define DEGC 16
#define NTOT (NB * NPG)      // 524288 nodes
#define ETOT (NTOT * DEGC)   // 8388608 edges
#define KK   (NPG / 2)       // 1024 kept per graph
#define EPG  (NPG * DEGC)    // 32768 edges per graph
#define NCB  16              // coarse buckets per graph (128 nodes each)
#define CBN  128             // nodes per coarse bucket
#define CAP  2560            // chunk capacity: mean 2048, sd 44 -> mean+11.6sd

// ---- K1: fused h = x@W (half-wave per node) + coarse edge partition.
//      One 1024-thread block per graph. h phase: 32 half-waves × 64 nodes,
//      1 KB/wave contiguous x reads (same pattern as the old k_h).
//      Partition phase: edges scattered to 16 append-frontiers (dense lines
//      -> no write amplification). Record: ebws = {w, src_local as float
//      bits}, ebe = (e_local<<7)|dst_low7. ----
__global__ __launch_bounds__(1024) void k_pre(const float* __restrict__ x,
                                              const float* __restrict__ W,
                                              const int* __restrict__ src,
                                              const int* __restrict__ dst,
                                              const float* __restrict__ w,
                                              float* __restrict__ h,
                                              int* __restrict__ cptr_g,
                                              int* __restrict__ ccnt_g,
                                              float2* __restrict__ ebws,
                                              int* __restrict__ ebe) {
    int g = blockIdx.x, t = threadIdx.x;
    __shared__ int ccnt[NCB];
    __shared__ int ccur[NCB];
    if (t < NCB) ccnt[t] = 0;
    // ---- h phase (no barrier needed before edge phases' LDS init above) ----
    {
        int lane = t & 63;
        int wv   = t >> 6;            // 0..15
        int half = lane >> 5;         // 0..1
        int sub  = lane & 31;
        int hw   = wv * 2 + half;     // half-wave id 0..31
        const float4* x4 = (const float4*)x;
        const float4* W4 = (const float4*)W;
        float4 wv4 = W4[sub];
        for (int r = 0; r < NPG / 32; r++) {
            int nl = r * 32 + hw;
            float4 xv = x4[((size_t)g * NPG + nl) * 32 + sub];
            float p = xv.x * wv4.x + xv.y * wv4.y + xv.z * wv4.z + xv.w * wv4.w;
            #pragma unroll
            for (int off = 16; off >= 1; off >>= 1) p += __shfl_xor(p, off, 64);
            if (sub == 0) h[(size_t)g * NPG + nl] = p;
        }
    }
    __syncthreads();
    const int*   dslab = dst + (size_t)g * EPG;
    const int*   sslab = src + (size_t)g * EPG;
    const float* wslab = w   + (size_t)g * EPG;
    // phase 1: count coarse buckets; keep local dst in registers (full unroll)
    int dloc[EPG / 1024];
    #pragma unroll
    for (int i = 0; i < EPG / 1024; i++) {
        dloc[i] = dslab[i * 1024 + t] - g * NPG;
        atomicAdd(&ccnt[dloc[i] >> 7], 1);
    }
    __syncthreads();
    // phase 2: tiny serial scan of 16
    if (t == 0) {
        int acc = 0;
        for (int b = 0; b < NCB; b++) {
            int c = ccnt[b];
            cptr_g[g * NCB + b] = acc;
            ccnt_g[g * NCB + b] = c;
            ccur[b] = acc;
            acc += c;
        }
    }
    __syncthreads();
    // phase 3: scatter to coarse frontiers
    size_t gb = (size_t)g * EPG;
    #pragma unroll
    for (int i = 0; i < EPG / 1024; i++) {
        int e = i * 1024 + t;
        int d = dloc[i];
        int pos = atomicAdd(&ccur[d >> 7], 1);
        ebe[gb + pos] = (e << 7) | (d & 127);
        float2 r;
        r.x = wslab[e];
        r.y = __int_as_float(sslab[e] - g * NPG);
        ebws[gb + pos] = r;
    }
}

// ---- K2: fine scatter + per-node sort + deg, one block per (graph, coarse
//      bucket). Stages the ~16 KB chunk in LDS, sorts each node's edges asc by
//      edge id (np.add.at order), computes deg in sorted order, writes the
//      sorted payload back IN PLACE (coalesced) -> ebws becomes pwsrc. ----
__global__ __launch_bounds__(256) void k_fine(const int* __restrict__ cptr_g,
                                              const int* __restrict__ ccnt_g,
                                              float2* ebws,            // read+write (in place)
                                              const int* __restrict__ ebe,
                                              int* __restrict__ ptr,
                                              int* __restrict__ cnt,
                                              float* __restrict__ is_arr) {
    __shared__ int   skey[CAP];
    __shared__ float sw[CAP];
    __shared__ float sy[CAP];
    __shared__ int cnt_f[CBN];
    __shared__ int cur_f[CBN];
    __shared__ int base_f[CBN];
    __shared__ int tmp[CBN];
    int g = blockIdx.x >> 4, cb = blockIdx.x & 15, t = threadIdx.x;
    int cb_base = cptr_g[g * NCB + cb];
    int ncb     = ccnt_g[g * NCB + cb];
    size_t gb = (size_t)g * EPG + cb_base;
    if (t < CBN) cnt_f[t] = 0;
    __syncthreads();
    // pass A: fine counts
    for (int i = t; i < ncb; i += 256) atomicAdd(&cnt_f[ebe[gb + i] & 127], 1);
    __syncthreads();
    // scan 128 (Hillis-Steele)
    if (t < CBN) tmp[t] = cnt_f[t];
    __syncthreads();
    for (int off = 1; off < CBN; off <<= 1) {
        int v = 0;
        if (t < CBN && t >= off) v = tmp[t - off];
        __syncthreads();
        if (t < CBN) tmp[t] += v;
        __syncthreads();
    }
    if (t < CBN) { base_f[t] = (t ? tmp[t - 1] : 0); cur_f[t] = base_f[t]; }
    __syncthreads();
    // pass B: scatter into LDS staging. skey = (e<<12)|slot (e<32768, slot<4096)
    for (int i = t; i < ncb; i += 256) {
        int ev = ebe[gb + i];
        int f  = ev & 127;
        int pos = atomicAdd(&cur_f[f], 1);
        if (pos < CAP) {
            float2 r = ebws[gb + i];
            skey[pos] = ((ev >> 7) << 12) | pos;
            sw[pos] = r.x;
            sy[pos] = r.y;
        }
    }
    __syncthreads();
    // per-node insertion sort by edge id + deg in sorted order
    if (t < CBN) {
        int b0 = base_f[t], k = cnt_f[t];
        for (int i = 1; i < k; i++) {
            int v = skey[b0 + i];
            int j = i - 1;
            while (j >= 0) {
                int u = skey[b0 + j];
                if (u > v) { skey[b0 + j + 1] = u; j--; } else break;
            }
            skey[b0 + j + 1] = v;
        }
        float s = 0.0f;
        for (int i = 0; i < k; i++) s += sw[skey[b0 + i] & 4095];
        float deg = s + 1.0f;                 // matches ref: segment_sum(...) + 1.0
        int node = g * NPG + cb * CBN + t;
        is_arr[node] = 1.0f / sqrtf(deg);
        ptr[node] = (int)gb + b0;
        cnt[node] = k;
    }
    __syncthreads();
    // coalesced in-place writeback of the sorted payload
    for (int i = t; i < ncb; i += 256) {
        int idx = skey[i] & 4095;
        float2 r;
        r.x = sw[idx];
        r.y = sy[idx];
        ebws[gb + i] = r;
    }
}

// ---- K3: fused tail — score + bitonic top-k + gather + edge remap, one
//      1024-thread block per graph. score/new_id/topk never touch global:
//      scores live in the (invertible) sort keys, new_id in LDS. ----
__global__ __launch_bounds__(1024) void k_final(const int* __restrict__ ptr,
                                                const int* __restrict__ cnt,
                                                const float2* __restrict__ pwsrc,
                                                const float* __restrict__ h,
                                                const float* __restrict__ is_arr,
                                                const float* __restrict__ x,
                                                const int* __restrict__ src,
                                                const int* __restrict__ dst,
                                                const float* __restrict__ w,
                                                float* __restrict__ out_px,
                                                float* __restrict__ out_pei0,
                                                float* __restrict__ out_pei1,
                                                float* __restrict__ out_pew,
                                                float* __restrict__ out_pngi) {
    __shared__ float sh_h[NPG];                 // 8 KB
    __shared__ float sh_is[NPG];                // 8 KB
    __shared__ unsigned long long key[NPG];     // 16 KB
    __shared__ int new_local[NPG];              // 8 KB
    __shared__ float gate[KK];                  // 4 KB
    __shared__ int   sel[KK];                   // 4 KB
    int g = blockIdx.x, t = threadIdx.x;
    // phase 1: stage h / is for the whole graph
    for (int i = t; i < NPG; i += 1024) {
        sh_h[i]  = h[(size_t)g * NPG + i];
        sh_is[i] = is_arr[(size_t)g * NPG + i];
    }
    __syncthreads();
    // phase 2: score, 2 nodes per thread (identical expression/order as before)
    float sc[2];
    #pragma unroll
    for (int r = 0; r < 2; r++) {
        int nl = t + r * 1024;
        int n = g * NPG + nl;
        int beg = ptr[n], k = cnt[n];
        float isd = sh_is[nl];
        float s = 0.0f;
        for (int i = 0; i < k; i++) {
            float2 rr = pwsrc[beg + i];
            int sl = __float_as_int(rr.y);
            float v = ((rr.x * sh_is[sl]) * isd) * sh_h[sl];  // ref rounding order
            s += v;
        }
        sc[r] = s + sh_h[nl] * (isd * isd);   // self-loop term, ref rounding order
    }
    __syncthreads();
    // phase 3: build sort keys (invertible score map) + init new_local
    #pragma unroll
    for (int r = 0; r < 2; r++) {
        int nl = t + r * 1024;
        unsigned int u = __float_as_uint(sc[r]);
        u = (u & 0x80000000u) ? ~u : (u | 0x80000000u);  // ascending-order map
        unsigned int ks = ~u;                            // descending primary
        key[nl] = ((unsigned long long)ks << 32) | (unsigned int)nl;
        new_local[nl] = -1;
    }
    __syncthreads();
    // phase 4: bitonic sort 2048 (desc score, asc index ties)
    for (int k = 2; k <= NPG; k <<= 1) {
        for (int j = k >> 1; j > 0; j >>= 1) {
            int i = ((t & ~(j - 1)) << 1) | (t & (j - 1));
            int p = i | j;
            bool up = ((i & k) == 0);
            unsigned long long a = key[i], c = key[p];
            if ((a > c) == up) { key[i] = c; key[p] = a; }
            __syncthreads();
        }
    }
    // phase 5: top-KK -> new_local, sel/gate (decode once per kept row), pngi
    {
        unsigned long long kk = key[t];
        int local = (int)(kk & 0xFFFFFFFFu);
        new_local[local] = t;
        unsigned int u = ~(unsigned int)(kk >> 32);
        unsigned int orig = (u & 0x80000000u) ? (u ^ 0x80000000u) : ~u;
        gate[t] = tanhf(__uint_as_float(orig));
        sel[t] = local;
        out_pngi[g * KK + t] = (float)g;
    }
    __syncthreads();
    // phase 6: pooled_x = x[node] * tanh(score) via LDS sel/gate broadcasts
    const float4* x4 = (const float4*)x;
    float4* o4 = (float4*)out_px;
    for (int q = t; q < KK * (DD / 4); q += 1024) {
        int row = q >> 5, c = q & 31;
        float gm = gate[row];
        int local = sel[row];
        float4 xv = x4[((size_t)g * NPG + local) * 32 + c];
        float4 o;
        o.x = xv.x * gm; o.y = xv.y * gm; o.z = xv.z * gm; o.w = xv.w * gm;
        o4[((size_t)g * KK + row) * 32 + c] = o;
    }
    // phase 7: edge remap + weight mask (new_id lookups in LDS)
    size_t eb = (size_t)g * EPG;
    for (int e = t; e < EPG; e += 1024) {
        int sl = src[eb + e] - g * NPG;
        int dl = dst[eb + e] - g * NPG;
        int ns = new_local[sl], nd = new_local[dl];
        bool m = (ns >= 0) && (nd >= 0);
        out_pei0[eb + e] = m ? (float)(g * KK + ns) : -1.0f;
        out_pei1[eb + e] = m ? (float)(g * KK + nd) : -1.0f;
        out_pew[eb + e]  = m ? w[eb + e] : 0.0f;
    }
}

extern "C" void kernel_launch(void* const* d_in, const int* in_sizes, int n_in,
                              void* d_out, int out_size, void* d_ws, size_t ws_size,
                              hipStream_t stream) {
    const float* x   = (const float*)d_in[0];
    const int*   ei  = (const int*)d_in[1];
    const float* w   = (const float*)d_in[2];
    // d_in[3] = node_graph_index (unused: graphs are uniform)
    const float* W   = (const float*)d_in[4];
    const int* src = ei;
    const int* dst = ei + ETOT;

    // workspace layout (offsets identical to the passing round-4/5 layout;
    // dead slots kept to preserve footprint)
    char* ws = (char*)d_ws;
    float*  h      = (float*)(ws);                 // N floats
    float*  is_arr = h + NTOT;                     // N floats
    float*  score_dead = is_arr + NTOT;            // N floats (unused)
    int*    cnt    = (int*)(score_dead + NTOT);    // N ints
    int*    ptr    = cnt + NTOT;                   // N ints
    int*    new_id_dead = ptr + NTOT;              // N ints (unused)
    int*    tkreg  = new_id_dead + NTOT;           // B*K ints (coarse tables alias)
    int*    ebe    = tkreg + (size_t)NB * KK;      // E ints (coarse records: keys)
    float2* ebws   = (float2*)(ebe + (size_t)ETOT);// E float2 (coarse records; becomes pwsrc)
    int* cptr_g = tkreg;                           // NB*16 ints
    int* ccnt_g = tkreg + NB * NCB;                // NB*16 ints

    // output layout (all float32)
    float* out_px   = (float*)d_out;                       // [B*K, D]
    float* out_pei0 = out_px + (size_t)NB * KK * DD;       // [E]
    float* out_pei1 = out_pei0 + ETOT;                     // [E]
    float* out_pew  = out_pei1 + ETOT;                     // [E]
    float* out_pngi = out_pew + ETOT;                      // [B*K]

    k_pre<<<NB, 1024, 0, stream>>>(x, W, src, dst, w, h, cptr_g, ccnt_g, ebws, ebe);
    k_fine<<<NB * NCB, 256, 0, stream>>>(cptr_g, ccnt_g, ebws, ebe, ptr, cnt, is_arr);
    k_final<<<NB, 1024, 0, stream>>>(ptr, cnt, ebws, h, is_arr, x, src, dst, w,
                                     out_px, out_pei0, out_pei1, out_pew, out_pngi);
}